// Round 2
// baseline (178.522 us; speedup 1.0000x reference)
//
#include <hip/hip_runtime.h>

// Flatten 2x2 blocks, fp32:
//   out[plane + i*1024 + 4j + 2r + s] = x[plane + (2i+r)*512 + 2j + s]
//
// Key identity (float2/float4 view): with global superrow I = g>>8 and
// column k = g&255 of output-float4 index g,
//   out4[g] = { x2[I*512 + k], x2[I*512 + 256 + k] }
// i.e. float2 loads are DENSE per wave (8B/lane x 64 = 512B/instr) and the
// float4 store is DENSE (16B/lane = 1KB/instr). No LDS, no barrier, no
// cross-lane movement — the merge is register-local.
//
// Round-5 theory: prior variants (59-60us) were load-MLP-bound: 4 wave-loads
// in flight, then a dependent LDS/barrier/store chain, one-shot 16KB blocks.
// This version keeps 16 independent loads in flight per wave (8 chunks deep),
// has zero synchronization, grid-strides 2 iterations per block, and uses
// nontemporal stores (output never re-read).
//
// Note: __builtin_nontemporal_store requires a NATIVE vector type (clang
// ext_vector_type), not HIP's float4 class — hence fx4 below.

namespace {
constexpr int UNROLL = 8;    // chunks (64 output float4s each) per wave per iter
constexpr int BLOCKS = 1536;
constexpr int ITERS  = 2;
// total chunks = BLOCKS * ITERS * 4 waves * UNROLL = 98304
//              = (32*3*512*512 / 4 floats-per-f4) / 64 lanes  ✓ exact cover
}

typedef float fx2 __attribute__((ext_vector_type(2)));
typedef float fx4 __attribute__((ext_vector_type(4)));

__global__ __launch_bounds__(256) void flatten2x2_deep(const float* __restrict__ x,
                                                       float* __restrict__ out) {
    const int tid  = (int)threadIdx.x;
    const int w    = tid >> 6;   // wave 0..3
    const int lane = tid & 63;

    const fx2* __restrict__ x2 = (const fx2*)x;
    fx4* __restrict__ o4       = (fx4*)out;

    for (int it = 0; it < ITERS; ++it) {
        const int chunk0 = ((int)blockIdx.x * ITERS + it) * (4 * UNROLL) + w * UNROLL;

        fx2 a[UNROLL], b[UNROLL];
        // --- issue all 16 loads back-to-back: deep, independent, dense ---
#pragma unroll
        for (int u = 0; u < UNROLL; ++u) {
            const int g  = (chunk0 + u) * 64 + lane;   // output float4 index
            const int f2 = g + ((g >> 8) << 8);        // = (g>>8)*512 + (g&255)
            a[u] = x2[f2];         // row 2i, float2 k   (dense across lanes)
            b[u] = x2[f2 + 256];   // row 2i+1, float2 k (dense across lanes)
        }
        // --- merge in registers, dense nontemporal stores ---
#pragma unroll
        for (int u = 0; u < UNROLL; ++u) {
            const int g = (chunk0 + u) * 64 + lane;
            fx4 v;
            v.x = a[u].x; v.y = a[u].y; v.z = b[u].x; v.w = b[u].y;
            __builtin_nontemporal_store(v, &o4[g]);
        }
    }
}

extern "C" void kernel_launch(void* const* d_in, const int* in_sizes, int n_in,
                              void* d_out, int out_size, void* d_ws, size_t ws_size,
                              hipStream_t stream) {
    const float* x = (const float*)d_in[0];
    float* out = (float*)d_out;
    flatten2x2_deep<<<BLOCKS, 256, 0, stream>>>(x, out);
}

// Round 3
// 165.061 us; speedup vs baseline: 1.0815x; 1.0815x over previous
//
#include <hip/hip_runtime.h>

// Flatten 2x2 blocks, fp32:
//   out[plane + i*1024 + 4j + 2r + s] = x[plane + (2i+r)*512 + 2j + s]
//
// Identity (float2/float4 view): with output-float4 index g, I = g>>8, k = g&255:
//   out4[g] = { x2[I*512 + k], x2[I*512 + 256 + k] }
// Both global sides dense, merge is register-local. No LDS, no barriers.
//
// Round-6 theory: three structurally distinct kernels all pin at 59-64 us
// (~2.4 TB/s visible HBM) while fill=6.8 TB/s, copy ubench=6.3 TB/s.
// Hypothesis: the harness's 403 MB poison fills leave L3 (256 MB MALL) fully
// dirty; our read/write allocations force dirty-line evictions -> ~150 MB of
// HBM writeback traffic INVISIBLE to TCC counters. Real traffic ~300 MB/60us
// ~= 5 TB/s, near ceiling. Fix: nontemporal on BOTH sides -> no allocation on
// miss -> no forced evictions. Predicted dur 35-45 us if theory holds.

namespace {
constexpr int UNROLL = 8;    // chunks (64 output float4s each) per wave
constexpr int BLOCKS = 3072; // x 4 waves x UNROLL chunks = 98304 = exact cover
}

typedef float fx2 __attribute__((ext_vector_type(2)));
typedef float fx4 __attribute__((ext_vector_type(4)));

__global__ __launch_bounds__(256) void flatten2x2_nt(const float* __restrict__ x,
                                                     float* __restrict__ out) {
    const int tid  = (int)threadIdx.x;
    const int w    = tid >> 6;   // wave 0..3
    const int lane = tid & 63;

    const fx2* __restrict__ x2 = (const fx2*)x;
    fx4* __restrict__ o4       = (fx4*)out;

    const int chunk0 = (int)blockIdx.x * (4 * UNROLL) + w * UNROLL;

    fx2 a[UNROLL], b[UNROLL];
    // --- 16 independent nontemporal loads, dense 512B/instr ---
#pragma unroll
    for (int u = 0; u < UNROLL; ++u) {
        const int g  = (chunk0 + u) * 64 + lane;   // output float4 index
        const int f2 = g + ((g >> 8) << 8);        // = (g>>8)*512 + (g&255)
        a[u] = __builtin_nontemporal_load(&x2[f2]);        // row 2i
        b[u] = __builtin_nontemporal_load(&x2[f2 + 256]);  // row 2i+1
    }
    // --- register merge, dense nontemporal stores 1KB/instr ---
#pragma unroll
    for (int u = 0; u < UNROLL; ++u) {
        const int g = (chunk0 + u) * 64 + lane;
        fx4 v;
        v.x = a[u].x; v.y = a[u].y; v.z = b[u].x; v.w = b[u].y;
        __builtin_nontemporal_store(v, &o4[g]);
    }
}

extern "C" void kernel_launch(void* const* d_in, const int* in_sizes, int n_in,
                              void* d_out, int out_size, void* d_ws, size_t ws_size,
                              hipStream_t stream) {
    const float* x = (const float*)d_in[0];
    float* out = (float*)d_out;
    flatten2x2_nt<<<BLOCKS, 256, 0, stream>>>(x, out);
}